// Round 9
// baseline (299.752 us; speedup 1.0000x reference)
//
#include <hip/hip_runtime.h>
#include <hip/hip_fp16.h>
#include <math.h>

// LinearCaps2d, BATCH=256, N = B_TYPES*H*W = 2048, C=10, POSE=16, 3 routing iters.
// R9: occupancy 2x via c-split waves (no atomic increase, no acc-combine).
//   grid 1024 = 128 ngrp (16 n) x 8 bgrp (32 b); 4 waves = 2 b-tiles x 2 c-groups(5 c).
//   Phase A (R7-verified transposed MFMA + fdot2 + 2 shfl) on own 5 c; logits exchanged
//   via f16 LDS (+1 barrier) for the 10-way softmax; phase B/flush on own 5 c.
// ws: s0,s1,s2 [40960] f32 (tiny -> cheap harness poison).

typedef _Float16 f16;
typedef _Float16 f16x2 __attribute__((ext_vector_type(2)));
typedef _Float16 f16x4 __attribute__((ext_vector_type(4)));
typedef _Float16 f16x8 __attribute__((ext_vector_type(8)));
typedef __fp16   h16x2 __attribute__((ext_vector_type(2)));
typedef float f32x4 __attribute__((ext_vector_type(4)));

__device__ __forceinline__ f16x2 pk(float a, float b) {
    h16x2 t = __builtin_amdgcn_cvt_pkrtz(a, b);
    return __builtin_bit_cast(f16x2, t);
}

#if __has_builtin(__builtin_amdgcn_fdot2)
__device__ __forceinline__ float FDOT2(f16x2 a, f16x2 b, float c) {
    return __builtin_amdgcn_fdot2(__builtin_bit_cast(h16x2, a),
                                  __builtin_bit_cast(h16x2, b), c, false);
}
#else
__device__ __forceinline__ float FDOT2(f16x2 a, f16x2 b, float c) {
    return c + (float)a[0] * (float)b[0] + (float)a[1] * (float)b[1];
}
#endif

constexpr int WS_ROW = 24;   // f16 row stride (16 i + 8 pad) = 48 B
constexpr int XS_ROW = 72;   // f16 row stride (4n x 16 i + 8 pad) = 144 B
constexpr int LG_ROW = 48;   // f16 per-b logit-exchange stride (4 n x 12)

__device__ __forceinline__ float xorsum4(float v) {
    v += __shfl_xor(v, 16, 64);
    v += __shfl_xor(v, 32, 64);
    return v;
}

__device__ __forceinline__ f16x4 cvt4(float4 w) {
    f16x2 a = pk(w.x, w.y);
    f16x2 b = pk(w.z, w.w);
    f16x4 r; r[0] = a[0]; r[1] = a[1]; r[2] = b[0]; r[3] = b[1];
    return r;
}

// grid: 1024 blocks = 128 n-groups (16 n) x 8 b-groups (32 b); 256 thr = 4 waves.
// wave = (t = b-tile 0..1, g = c-group 0..1).
template<int PASS>
__global__ __launch_bounds__(256, 4)
void pass_k(const float* __restrict__ poses, const float* __restrict__ weight,
            const float* __restrict__ bias,
            const float* __restrict__ sp0, const float* __restrict__ sp1,
            float* __restrict__ s_dst)
{
    __shared__ f16 Ws[640 * WS_ROW];   // 30720 B  (4n x 160 rows per iter)
    __shared__ f16 xs[32 * XS_ROW];    //  4608 B  (32 b x 4 n)
    __shared__ f16 lgx[32 * LG_ROW];   //  3072 B  (logit exchange)
    // total 38400 B -> 4 blocks/CU

    const int tid  = threadIdx.x;
    const int blk  = blockIdx.x;
    const int ngrp = blk >> 3;            // 128 n-groups
    const int b0   = (blk & 7) * 32;      // 8 b-groups of 32
    const int wave = tid >> 6;
    const int lane = tid & 63;
    const int q    = lane >> 4;
    const int lo   = lane & 15;
    const int t    = wave & 1;            // b-tile
    const int g    = wave >> 1;           // c-group (c = g*5 + cc)
    const int c0   = g * 5;
    const int go   = (1 - g) * 5;         // partner c-offset
    const int wtb  = t * 16;
    const int bg   = b0 + wtb;
    const int nl0  = q >> 1;              // phase B K packing
    const int iq   = (q & 1) * 8;

    // ---- inline squash: vsp[cc] = v[b=bg+lo][c=c0+cc][o=q*4..q*4+3] packed f16
    f16x2 vsp[5][2];
    if (PASS >= 1) {
        const int rowb = (bg + lo) * 10;
        #pragma unroll
        for (int cc = 0; cc < 5; ++cc) {
            const int c = c0 + cc;
            float4 bb = *(const float4*)(bias + c * 16 + q * 4);
            float4 sa = *(const float4*)(sp0 + (size_t)(rowb + c) * 16 + q * 4);
            float t0 = sa.x + bb.x, t1 = sa.y + bb.y, t2 = sa.z + bb.z, t3 = sa.w + bb.w;
            float n2 = xorsum4(t0*t0 + t1*t1 + t2*t2 + t3*t3);
            float sc = n2 / (1.f + n2) * rsqrtf(n2 + 1e-8f);
            float v0 = sc*t0, v1 = sc*t1, v2 = sc*t2, v3 = sc*t3;
            if (PASS == 2) {
                float4 sb = *(const float4*)(sp1 + (size_t)(rowb + c) * 16 + q * 4);
                float u0 = sb.x + bb.x, u1 = sb.y + bb.y, u2 = sb.z + bb.z, u3 = sb.w + bb.w;
                float m2 = xorsum4(u0*u0 + u1*u1 + u2*u2 + u3*u3);
                float sc2 = m2 / (1.f + m2) * rsqrtf(m2 + 1e-8f);
                v0 += sc2*u0; v1 += sc2*u1; v2 += sc2*u2; v3 += sc2*u3;
            }
            vsp[cc][0] = pk(v0, v1);
            vsp[cc][1] = pk(v2, v3);
        }
    }

    // ---- staging (software-pipelined): per iter 4 n (W: 10240 f32, x: 32b x 64 f32)
    float4 wreg[10];
    float4 xreg[2];
    const int b_loc = tid >> 3, part = tid & 7;   // 32 b x 8 parts (8 floats each)

    auto load_iter = [&](int l) {
        const float* wp = weight + (size_t)(ngrp * 4 + l) * 10240;
        #pragma unroll
        for (int k = 0; k < 10; ++k) wreg[k] = ((const float4*)wp)[tid + k * 256];
        const float* xp = poses + (size_t)(b0 + b_loc) * 32768
                          + (size_t)(ngrp * 16 + l * 4) * 16 + part * 8;
        xreg[0] = ((const float4*)xp)[0];
        xreg[1] = ((const float4*)xp)[1];
    };
    auto store_iter = [&]() {
        #pragma unroll
        for (int k = 0; k < 10; ++k) {
            const int f = tid + k * 256;          // float4 index in [0,2560)
            *(f16x4*)&Ws[(f >> 2) * WS_ROW + (f & 3) * 4] = cvt4(wreg[k]);
        }
        f16x4 r0 = cvt4(xreg[0]), r1 = cvt4(xreg[1]);
        f16x8 r = __builtin_shufflevector(r0, r1, 0, 1, 2, 3, 4, 5, 6, 7);
        *(f16x8*)&xs[b_loc * XS_ROW + part * 8] = r;
    };

    f32x4 acc[5];
    #pragma unroll
    for (int cc = 0; cc < 5; ++cc) acc[cc] = (f32x4){0.f, 0.f, 0.f, 0.f};

    f16x2 cf[5][2];     // coeff packed over n-pairs
    float lgs[4][5];    // own logits per (n, cc), replicated over q

    load_iter(0);

    for (int l = 0; l < 4; ++l) {
        __syncthreads();
        store_iter();
        if (l + 1 < 4) load_iter(l + 1);
        __syncthreads();

        if (PASS >= 1) {
            // ---- phase A: votes^T (D[o][b]) on own 5 c; logits = fdot2 + 2 shfl
            #pragma unroll
            for (int n = 0; n < 4; ++n) {
                f16x4 bx = *(const f16x4*)&xs[(wtb + lo) * XS_ROW + n * 16 + q * 4];
                #pragma unroll
                for (int cc = 0; cc < 5; ++cc) {
                    f16x4 aw = *(const f16x4*)&Ws[((n * 10 + c0 + cc) * 16 + lo) * WS_ROW + q * 4];
                    f32x4 D = __builtin_amdgcn_mfma_f32_16x16x16f16(
                        aw, bx, (f32x4){0.f, 0.f, 0.f, 0.f}, 0, 0, 0);
                    float p = FDOT2(pk(D[0], D[1]), vsp[cc][0], 0.f);
                    p = FDOT2(pk(D[2], D[3]), vsp[cc][1], p);
                    lgs[n][cc] = xorsum4(p);
                }
                if (q == 0) {
                    #pragma unroll
                    for (int cc = 0; cc < 5; ++cc)
                        lgx[(wtb + lo) * LG_ROW + n * 12 + c0 + cc] = (f16)lgs[n][cc];
                }
            }
            __syncthreads();   // logits exchanged

            // ---- 10-way softmax per (b,n); keep own 5 coeffs
            #pragma unroll
            for (int n = 0; n < 4; ++n) {
                float pf[5];
                #pragma unroll
                for (int cc = 0; cc < 5; ++cc)
                    pf[cc] = (float)lgx[(wtb + lo) * LG_ROW + n * 12 + go + cc];
                float m = lgs[n][0];
                #pragma unroll
                for (int cc = 1; cc < 5; ++cc) m = fmaxf(m, lgs[n][cc]);
                #pragma unroll
                for (int cc = 0; cc < 5; ++cc) m = fmaxf(m, pf[cc]);
                float sum = 0.f;
                float eo[5];
                #pragma unroll
                for (int cc = 0; cc < 5; ++cc) { eo[cc] = __expf(lgs[n][cc] - m); sum += eo[cc]; }
                #pragma unroll
                for (int cc = 0; cc < 5; ++cc) sum += __expf(pf[cc] - m);
                const float inv = 1.f / sum;
                if (n & 1) {
                    #pragma unroll
                    for (int cc = 0; cc < 5; ++cc)
                        cf[cc][n >> 1][1] = (f16)(eo[cc] * inv);
                } else {
                    #pragma unroll
                    for (int cc = 0; cc < 5; ++cc) {
                        f16x2 z; z[0] = (f16)(eo[cc] * inv); z[1] = (f16)0.f;
                        cf[cc][n >> 1] = z;
                    }
                }
            }
        }

        // ---- phase B: acc += (coeff*x) W on own 5 c  (K=32 = 2 n x 16 i)
        f16x8 xa[2];
        #pragma unroll
        for (int np = 0; np < 2; ++np)
            xa[np] = *(const f16x8*)&xs[(wtb + lo) * XS_ROW + (np * 2 + nl0) * 16 + iq];
        #pragma unroll
        for (int cc = 0; cc < 5; ++cc) {
            #pragma unroll
            for (int np = 0; np < 2; ++np) {
                f16 ch;
                if (PASS == 0) {
                    ch = (f16)0.1f;
                } else {
                    union { f16x2 h2; unsigned u; } cu; cu.h2 = cf[cc][np];
                    unsigned hv = nl0 ? (cu.u >> 16) : (cu.u & 0xffffu);
                    union { unsigned short s; f16 hh; } hu; hu.s = (unsigned short)hv;
                    ch = hu.hh;
                }
                const int n_loc = np * 2 + nl0;
                f16x8 bw = *(const f16x8*)&Ws[((n_loc * 10 + c0 + cc) * 16 + lo) * WS_ROW + iq];
                f16x8 av = xa[np] * ch;
                acc[cc] = __builtin_amdgcn_mfma_f32_16x16x32_f16(av, bw, acc[cc], 0, 0, 0);
            }
        }
    }

    // ---- atomic flush: own 5 c, rows b = bg+q*4+r, col o = lo
    #pragma unroll
    for (int cc = 0; cc < 5; ++cc) {
        float* sp = s_dst + ((size_t)(bg + q * 4) * 10 + c0 + cc) * 16 + lo;
        unsafeAtomicAdd(sp + 0 * 160, acc[cc][0]);
        unsafeAtomicAdd(sp + 1 * 160, acc[cc][1]);
        unsafeAtomicAdd(sp + 2 * 160, acc[cc][2]);
        unsafeAtomicAdd(sp + 3 * 160, acc[cc][3]);
    }
}

// final squash: 2560 rows, one (b,c) per thread (verified R3/R7).
__global__ __launch_bounds__(256)
void epi_k(const float* __restrict__ s2, const float* __restrict__ bias,
           float* __restrict__ out)
{
    const int t = blockIdx.x * 256 + threadIdx.x;
    if (t >= 2560) return;
    const int c = t % 10;
    const float* sp = s2 + (size_t)t * 16;
    const float* bp = bias + c * 16;
    float sv[16];
    float n2 = 0.f;
    #pragma unroll
    for (int o = 0; o < 16; ++o) { float v = sp[o] + bp[o]; sv[o] = v; n2 += v * v; }
    const float scale = n2 / (1.f + n2) * rsqrtf(n2 + 1e-8f);
    float a2 = 0.f;
    #pragma unroll
    for (int o = 0; o < 16; ++o) {
        float v = scale * sv[o];
        out[(size_t)t * 16 + o] = v;
        a2 += v * v;
    }
    out[40960 + t] = sqrtf(a2 + 1e-8f);
}

extern "C" void kernel_launch(void* const* d_in, const int* in_sizes, int n_in,
                              void* d_out, int out_size, void* d_ws, size_t ws_size,
                              hipStream_t stream)
{
    const float* poses  = (const float*)d_in[0];
    // d_in[1] (input_caps_activations) unused by the reference.
    const float* weight = (const float*)d_in[2];
    const float* bias   = (const float*)d_in[3];
    float* out = (float*)d_out;
    float* s0 = (float*)d_ws;
    float* s1 = s0 + 40960;
    float* s2 = s1 + 40960;

    (void)hipMemsetAsync(d_ws, 0, 3 * 40960 * sizeof(float), stream);

    pass_k<0><<<1024, 256, 0, stream>>>(poses, weight, bias, nullptr, nullptr, s0);
    pass_k<1><<<1024, 256, 0, stream>>>(poses, weight, bias, s0, nullptr, s1);
    pass_k<2><<<1024, 256, 0, stream>>>(poses, weight, bias, s0, s1, s2);
    epi_k<<<10, 256, 0, stream>>>(s2, bias, out);
}